// Round 2
// baseline (299.898 us; speedup 1.0000x reference)
//
#include <hip/hip_runtime.h>
#include <cstdint>

#define NNODES 100000
#define NEDGES 1600000
#define NBKT   196          // ceil(NNODES / 512); bucket = dst >> 9
#define CAP    9216         // per-bucket capacity: mean 8192 + ~11 sigma
#define BIN_CHUNK 4096
#define GBIN ((NEDGES + BIN_CHUNK - 1) / BIN_CHUNK)   // 391
#define GCVT (NNODES * 128 / 8 / 256)                 // 6250 (8 floats/thread)

typedef __attribute__((ext_vector_type(8))) __bf16 bf16x8;
typedef __attribute__((ext_vector_type(4))) float f32x4;
typedef short v2s __attribute__((ext_vector_type(2)));

__device__ __forceinline__ unsigned short f2bf_rne(float f) {
    unsigned int u = __float_as_uint(f);
    u += 0x7fffu + ((u >> 16) & 1u);
    return (unsigned short)(u >> 16);
}
// involutive monotone map: bf16 float order <-> signed i16 order (per packed half)
__device__ __forceinline__ unsigned encdec(unsigned u) {
    return u ^ (((u & 0x80008000u) >> 15) * 0x7FFFu);
}
__device__ __forceinline__ unsigned pkmax(unsigned a, unsigned b) {
    v2s r = __builtin_elementwise_max(__builtin_bit_cast(v2s, a), __builtin_bit_cast(v2s, b));
    return __builtin_bit_cast(unsigned, r);
}

// ---------------- prep1: zero bucketFill + pack weights into MFMA B-fragment
__global__ __launch_bounds__(256) void prep1_kernel(
        const float* __restrict__ W1l, const float* __restrict__ W1r,
        const float* __restrict__ W2l, const float* __restrict__ W2r,
        uint4* __restrict__ Wf1, uint4* __restrict__ Wf2,
        int* __restrict__ bucketFill) {
    if (blockIdx.x == 24) { bucketFill[threadIdx.x] = 0; return; }
    int t = blockIdx.x * 256 + threadIdx.x;   // 0..6143
    unsigned short s[8];
    if (t < 4096) {                           // layer 1: BN=128, NT=8
        int h = t >> 11, kt = (t >> 9) & 3, nt = (t >> 6) & 7, lane = t & 63;
        const float* W = h ? W1r : W1l;
        int k0 = kt * 32 + (lane >> 4) * 8;
        int col = nt * 16 + (lane & 15);
#pragma unroll
        for (int j = 0; j < 8; ++j) s[j] = f2bf_rne(W[(k0 + j) * 128 + col]);
        uint4 o;
        o.x = (unsigned)s[0] | ((unsigned)s[1] << 16);
        o.y = (unsigned)s[2] | ((unsigned)s[3] << 16);
        o.z = (unsigned)s[4] | ((unsigned)s[5] << 16);
        o.w = (unsigned)s[6] | ((unsigned)s[7] << 16);
        Wf1[t] = o;
    } else {                                  // layer 2: BN=64, NT=4
        int u = t - 4096;                     // 0..2047
        int h = u >> 10, kt = (u >> 8) & 3, nt = (u >> 6) & 3, lane = u & 63;
        const float* W = h ? W2r : W2l;
        int k0 = kt * 32 + (lane >> 4) * 8;
        int col = nt * 16 + (lane & 15);
#pragma unroll
        for (int j = 0; j < 8; ++j) s[j] = f2bf_rne(W[(k0 + j) * 64 + col]);
        uint4 o;
        o.x = (unsigned)s[0] | ((unsigned)s[1] << 16);
        o.y = (unsigned)s[2] | ((unsigned)s[3] << 16);
        o.z = (unsigned)s[4] | ((unsigned)s[5] << 16);
        o.w = (unsigned)s[6] | ((unsigned)s[7] << 16);
        Wf2[u] = o;
    }
}

// ---------------- prep2: bin edges (blocks [0,GBIN)) + encode x (rest) --------
__global__ __launch_bounds__(256) void prep2_kernel(
        const int* __restrict__ src, const int* __restrict__ dst,
        unsigned int* __restrict__ binArr, int* __restrict__ bucketFill,
        const float4* __restrict__ xin, uint4* __restrict__ xeout, int nE) {
    if (blockIdx.x >= GBIN) {
        int i = (blockIdx.x - GBIN) * 256 + threadIdx.x;  // < 1.6M
        float4 v0 = xin[(size_t)2 * i], v1 = xin[(size_t)2 * i + 1];
        uint4 o;
        o.x = encdec((unsigned)f2bf_rne(v0.x) | ((unsigned)f2bf_rne(v0.y) << 16));
        o.y = encdec((unsigned)f2bf_rne(v0.z) | ((unsigned)f2bf_rne(v0.w) << 16));
        o.z = encdec((unsigned)f2bf_rne(v1.x) | ((unsigned)f2bf_rne(v1.y) << 16));
        o.w = encdec((unsigned)f2bf_rne(v1.z) | ((unsigned)f2bf_rne(v1.w) << 16));
        xeout[i] = o;
        return;
    }
    // ---- bin: entry = (dst&511)<<17 | src ----
    __shared__ unsigned int stage[BIN_CHUNK];
    __shared__ unsigned char bof[BIN_CHUNK];
    __shared__ int cnt[256], cstart[256], cfill[256], gbase[256];
    const int tid = threadIdx.x;
    const int blockStart = blockIdx.x * BIN_CHUNK;
    const int chunkN = min(BIN_CHUNK, nE - blockStart);
    cnt[tid] = 0;
    __syncthreads();
    int myd[16], mys[16];
#pragma unroll
    for (int i = 0; i < 16; ++i) {
        int idx = i * 256 + tid;
        if (idx < chunkN) {
            myd[i] = dst[blockStart + idx];
            mys[i] = src[blockStart + idx];
            atomicAdd(&cnt[myd[i] >> 9], 1);
        }
    }
    __syncthreads();
    int v = cnt[tid];
    for (int off = 1; off < 256; off <<= 1) {
        int add = (tid >= off) ? cnt[tid - off] : 0;
        __syncthreads();
        cnt[tid] += add;
        __syncthreads();
    }
    cstart[tid] = cnt[tid] - v;
    cfill[tid] = cnt[tid] - v;
    if (tid < NBKT && v > 0) gbase[tid] = atomicAdd(&bucketFill[tid], v);
    __syncthreads();
#pragma unroll
    for (int i = 0; i < 16; ++i) {
        int idx = i * 256 + tid;
        if (idx < chunkN) {
            int b = myd[i] >> 9;
            int p = atomicAdd(&cfill[b], 1);
            stage[p] = ((unsigned)(myd[i] & 511) << 17) | (unsigned)mys[i];
            bof[p] = (unsigned char)b;
        }
    }
    __syncthreads();
#pragma unroll
    for (int i = 0; i < 16; ++i) {
        int idx = i * 256 + tid;
        if (idx < chunkN) {
            int b = bof[idx];
            int slot = gbase[b] + (idx - cstart[b]);
            if (slot < CAP) binArr[(size_t)b * CAP + slot] = stage[idx];
        }
    }
}

// ---------------- per-bucket CSR build, all in LDS ----------------
__global__ __launch_bounds__(512) void build_csr_kernel(
        const unsigned int* __restrict__ binArr, const int* __restrict__ bucketFill,
        unsigned int* __restrict__ sortedSrc,
        int* __restrict__ rowBeg, int* __restrict__ rowEnd) {
    __shared__ unsigned int stage[CAP];
    __shared__ int ncnt[512], nstart[512];
    const int b = blockIdx.x;
    const int t = threadIdx.x;
    const int cnt_b = min(bucketFill[b], CAP);
    ncnt[t] = 0;
    __syncthreads();
    for (int i = t; i < cnt_b; i += 512) {
        unsigned int e = binArr[(size_t)b * CAP + i];
        stage[i] = e;
        atomicAdd(&ncnt[e >> 17], 1);
    }
    __syncthreads();
    int v = ncnt[t];
    for (int off = 1; off < 512; off <<= 1) {
        int add = (t >= off) ? ncnt[t - off] : 0;
        __syncthreads();
        ncnt[t] += add;
        __syncthreads();
    }
    int start = ncnt[t] - v;
    nstart[t] = start;
    int n = (b << 9) + t;
    if (n < NNODES) {
        rowBeg[n] = b * CAP + start;
        rowEnd[n] = b * CAP + start + v;
    }
    __syncthreads();
    for (int i = t; i < cnt_b; i += 512) {
        unsigned int e = stage[i];
        int p = atomicAdd(&nstart[e >> 17], 1);
        sortedSrc[(size_t)b * CAP + p] = e & 0x1FFFFu;
    }
}

// ---------------- aggregation: software-pipelined, 4 node-pairs per wave ----
// Per pair: 8 uint4 gathers in flight; next pair's rowBeg/rowEnd issued before
// the gathers, next pair's sortedSrc ids issued after (FIFO => counted vmcnt
// waits never drain the pipeline). Output stays ENCODED.
__global__ __launch_bounds__(256, 4) void aggregate_pipe(
        const uint4* __restrict__ xe4,          // [M][16] encoded bf16
        const int* __restrict__ rowBeg,
        const int* __restrict__ rowEnd,
        const unsigned int* __restrict__ sortedSrc,
        uint4* __restrict__ aggrE) {            // [M][16] encoded bf16
    const int lane = threadIdx.x & 63;
    const int grp = lane >> 4;
    const int col = lane & 15;
    const int base = blockIdx.x * 32 + (threadIdx.x >> 6) * 8;   // 8 nodes/wave
    // grid is exact: NNODES/32 == 3125 blocks, nodes 0..99999 all valid.

    // prologue: pair 0 bounds + ids
    int begA = rowBeg[base + 0], endA = rowEnd[base + 0];
    int begB = rowBeg[base + 1], endB = rowEnd[base + 1];
    int idA = (endA > begA) ? (int)sortedSrc[min(begA + lane, endA - 1)] : 0;
    int idB = (endB > begB) ? (int)sortedSrc[min(begB + lane, endB - 1)] : 0;

    for (int p = 0; p < 4; ++p) {
        const int nA = base + 2 * p, nB = nA + 1;
        const int mA = endA - begA, mB = endB - begB;

        // prefetch next pair's row bounds (independent, issued before gathers)
        int begA2 = 0, endA2 = 0, begB2 = 0, endB2 = 0;
        if (p < 3) {
            begA2 = rowBeg[nA + 2]; endA2 = rowEnd[nA + 2];
            begB2 = rowBeg[nB + 2]; endB2 = rowEnd[nB + 2];
        }

        // round 0: unconditional 8 gathers (ids are clamp-replicated, safe)
        int sA0 = __shfl(idA, grp),     sA1 = __shfl(idA, 4 + grp);
        int sA2 = __shfl(idA, 8 + grp), sA3 = __shfl(idA, 12 + grp);
        int sB0 = __shfl(idB, grp),     sB1 = __shfl(idB, 4 + grp);
        int sB2 = __shfl(idB, 8 + grp), sB3 = __shfl(idB, 12 + grp);
        uint4 pA0 = xe4[(size_t)sA0 * 16 + col];
        uint4 pA1 = xe4[(size_t)sA1 * 16 + col];
        uint4 pA2 = xe4[(size_t)sA2 * 16 + col];
        uint4 pA3 = xe4[(size_t)sA3 * 16 + col];
        uint4 pB0 = xe4[(size_t)sB0 * 16 + col];
        uint4 pB1 = xe4[(size_t)sB1 * 16 + col];
        uint4 pB2 = xe4[(size_t)sB2 * 16 + col];
        uint4 pB3 = xe4[(size_t)sB3 * 16 + col];

        // prefetch next pair's ids while the gathers are in flight
        int idA2 = 0, idB2 = 0;
        if (p < 3) {
            idA2 = (endA2 > begA2) ? (int)sortedSrc[min(begA2 + lane, endA2 - 1)] : 0;
            idB2 = (endB2 > begB2) ? (int)sortedSrc[min(begB2 + lane, endB2 - 1)] : 0;
        }

        // accumulators init directly from round 0
        unsigned aA0 = pkmax(pkmax(pA0.x, pA1.x), pkmax(pA2.x, pA3.x));
        unsigned aA1 = pkmax(pkmax(pA0.y, pA1.y), pkmax(pA2.y, pA3.y));
        unsigned aA2 = pkmax(pkmax(pA0.z, pA1.z), pkmax(pA2.z, pA3.z));
        unsigned aA3 = pkmax(pkmax(pA0.w, pA1.w), pkmax(pA2.w, pA3.w));
        unsigned aB0 = pkmax(pkmax(pB0.x, pB1.x), pkmax(pB2.x, pB3.x));
        unsigned aB1 = pkmax(pkmax(pB0.y, pB1.y), pkmax(pB2.y, pB3.y));
        unsigned aB2 = pkmax(pkmax(pB0.z, pB1.z), pkmax(pB2.z, pB3.z));
        unsigned aB3 = pkmax(pkmax(pB0.w, pB1.w), pkmax(pB2.w, pB3.w));

        // extra rounds for degree 17..64
        const int cA = min(mA, 64), cB = min(mB, 64);
        const int mm = max(cA, cB);
        for (int j = 16; j < mm; j += 16) {
            const bool doA = j < cA, doB = j < cB;
            uint4 qA0, qA1, qA2, qA3, qB0, qB1, qB2, qB3;
            if (doA) {
                int s0 = __shfl(idA, j + grp);
                int s1 = __shfl(idA, j + 4 + grp);
                int s2 = __shfl(idA, j + 8 + grp);
                int s3 = __shfl(idA, j + 12 + grp);
                qA0 = xe4[(size_t)s0 * 16 + col];
                qA1 = xe4[(size_t)s1 * 16 + col];
                qA2 = xe4[(size_t)s2 * 16 + col];
                qA3 = xe4[(size_t)s3 * 16 + col];
            }
            if (doB) {
                int s0 = __shfl(idB, j + grp);
                int s1 = __shfl(idB, j + 4 + grp);
                int s2 = __shfl(idB, j + 8 + grp);
                int s3 = __shfl(idB, j + 12 + grp);
                qB0 = xe4[(size_t)s0 * 16 + col];
                qB1 = xe4[(size_t)s1 * 16 + col];
                qB2 = xe4[(size_t)s2 * 16 + col];
                qB3 = xe4[(size_t)s3 * 16 + col];
            }
            if (doA) {
                aA0 = pkmax(aA0, pkmax(pkmax(qA0.x, qA1.x), pkmax(qA2.x, qA3.x)));
                aA1 = pkmax(aA1, pkmax(pkmax(qA0.y, qA1.y), pkmax(qA2.y, qA3.y)));
                aA2 = pkmax(aA2, pkmax(pkmax(qA0.z, qA1.z), pkmax(qA2.z, qA3.z)));
                aA3 = pkmax(aA3, pkmax(pkmax(qA0.w, qA1.w), pkmax(qA2.w, qA3.w)));
            }
            if (doB) {
                aB0 = pkmax(aB0, pkmax(pkmax(qB0.x, qB1.x), pkmax(qB2.x, qB3.x)));
                aB1 = pkmax(aB1, pkmax(pkmax(qB0.y, qB1.y), pkmax(qB2.y, qB3.y)));
                aB2 = pkmax(aB2, pkmax(pkmax(qB0.z, qB1.z), pkmax(qB2.z, qB3.z)));
                aB3 = pkmax(aB3, pkmax(pkmax(qB0.w, qB1.w), pkmax(qB2.w, qB3.w)));
            }
        }
        // degree > 64 tails (Poisson(16): essentially never, kept for safety)
        for (int bs = begA + 64; bs < endA; bs += 64) {
            int bid = (int)sortedSrc[min(bs + lane, endA - 1)];
            const int m = min(endA - bs, 64);
            for (int j = 0; j < m; j += 16) {
                int s0 = __shfl(bid, j + grp);
                int s1 = __shfl(bid, j + 4 + grp);
                int s2 = __shfl(bid, j + 8 + grp);
                int s3 = __shfl(bid, j + 12 + grp);
                uint4 q0 = xe4[(size_t)s0 * 16 + col];
                uint4 q1 = xe4[(size_t)s1 * 16 + col];
                uint4 q2 = xe4[(size_t)s2 * 16 + col];
                uint4 q3 = xe4[(size_t)s3 * 16 + col];
                aA0 = pkmax(aA0, pkmax(pkmax(q0.x, q1.x), pkmax(q2.x, q3.x)));
                aA1 = pkmax(aA1, pkmax(pkmax(q0.y, q1.y), pkmax(q2.y, q3.y)));
                aA2 = pkmax(aA2, pkmax(pkmax(q0.z, q1.z), pkmax(q2.z, q3.z)));
                aA3 = pkmax(aA3, pkmax(pkmax(q0.w, q1.w), pkmax(q2.w, q3.w)));
            }
        }
        for (int bs = begB + 64; bs < endB; bs += 64) {
            int bid = (int)sortedSrc[min(bs + lane, endB - 1)];
            const int m = min(endB - bs, 64);
            for (int j = 0; j < m; j += 16) {
                int s0 = __shfl(bid, j + grp);
                int s1 = __shfl(bid, j + 4 + grp);
                int s2 = __shfl(bid, j + 8 + grp);
                int s3 = __shfl(bid, j + 12 + grp);
                uint4 q0 = xe4[(size_t)s0 * 16 + col];
                uint4 q1 = xe4[(size_t)s1 * 16 + col];
                uint4 q2 = xe4[(size_t)s2 * 16 + col];
                uint4 q3 = xe4[(size_t)s3 * 16 + col];
                aB0 = pkmax(aB0, pkmax(pkmax(q0.x, q1.x), pkmax(q2.x, q3.x)));
                aB1 = pkmax(aB1, pkmax(pkmax(q0.y, q1.y), pkmax(q2.y, q3.y)));
                aB2 = pkmax(aB2, pkmax(pkmax(q0.z, q1.z), pkmax(q2.z, q3.z)));
                aB3 = pkmax(aB3, pkmax(pkmax(q0.w, q1.w), pkmax(q2.w, q3.w)));
            }
        }

        // merge the 4 edge-groups (lane bits 4,5)
        aA0 = pkmax(aA0, (unsigned)__shfl_xor((int)aA0, 16));
        aA1 = pkmax(aA1, (unsigned)__shfl_xor((int)aA1, 16));
        aA2 = pkmax(aA2, (unsigned)__shfl_xor((int)aA2, 16));
        aA3 = pkmax(aA3, (unsigned)__shfl_xor((int)aA3, 16));
        aB0 = pkmax(aB0, (unsigned)__shfl_xor((int)aB0, 16));
        aB1 = pkmax(aB1, (unsigned)__shfl_xor((int)aB1, 16));
        aB2 = pkmax(aB2, (unsigned)__shfl_xor((int)aB2, 16));
        aB3 = pkmax(aB3, (unsigned)__shfl_xor((int)aB3, 16));
        aA0 = pkmax(aA0, (unsigned)__shfl_xor((int)aA0, 32));
        aA1 = pkmax(aA1, (unsigned)__shfl_xor((int)aA1, 32));
        aA2 = pkmax(aA2, (unsigned)__shfl_xor((int)aA2, 32));
        aA3 = pkmax(aA3, (unsigned)__shfl_xor((int)aA3, 32));
        aB0 = pkmax(aB0, (unsigned)__shfl_xor((int)aB0, 32));
        aB1 = pkmax(aB1, (unsigned)__shfl_xor((int)aB1, 32));
        aB2 = pkmax(aB2, (unsigned)__shfl_xor((int)aB2, 32));
        aB3 = pkmax(aB3, (unsigned)__shfl_xor((int)aB3, 32));

        // lanes 0..15 write node A's row, lanes 16..31 write node B's
        if (lane < 16) {
            uint4 o;
            if (mA > 0) { o.x = aA0; o.y = aA1; o.z = aA2; o.w = aA3; }
            else        { o.x = o.y = o.z = o.w = 0u; }          // enc(0)==0
            aggrE[(size_t)nA * 16 + lane] = o;
        } else if (lane < 32) {
            uint4 o;
            if (mB > 0) { o.x = aB0; o.y = aB1; o.z = aB2; o.w = aB3; }
            else        { o.x = o.y = o.z = o.w = 0u; }
            aggrE[(size_t)nB * 16 + (lane - 16)] = o;
        }

        // rotate pipeline registers
        begA = begA2; endA = endA2; begB = begB2; endB = endB2;
        idA = idA2; idB = idB2;
    }
}

// ---------------- lean SAGE GEMM: no LDS, no barriers ----------------
template<int BN, bool RELU, bool ENCOUT, typename OutT>
__global__ __launch_bounds__(256, 4) void sage_gemm_lean(
        const uint4* __restrict__ AggE,            // [M][16] encoded bf16
        const uint4* __restrict__ RootE,           // [M][16] encoded bf16
        const uint4* __restrict__ Wf,              // fragment-packed weights
        const float* __restrict__ bias,            // [BN] f32
        OutT* __restrict__ C,                      // [M][BN]
        int M) {
    constexpr int NT = BN / 16;
    const int tid = threadIdx.x;
    const int w = tid >> 6;
    const int lane = tid & 63;
    const int quad = lane >> 4;
    const int mrow = lane & 15;
    const int base0 = blockIdx.x * 128 + w * 32;

    const int r0 = min(base0 + mrow, M - 1);
    const int r1 = min(base0 + 16 + mrow, M - 1);

    f32x4 acc[2][NT];
#pragma unroll
    for (int mt = 0; mt < 2; ++mt)
#pragma unroll
        for (int nt = 0; nt < NT; ++nt) acc[mt][nt] = (f32x4){0.f, 0.f, 0.f, 0.f};

#pragma unroll
    for (int kt = 0; kt < 4; ++kt) {
        uint4 ta0 = AggE[(size_t)r0 * 16 + kt * 4 + quad];
        uint4 ta1 = AggE[(size_t)r1 * 16 + kt * 4 + quad];
        uint4 tr0 = RootE[(size_t)r0 * 16 + kt * 4 + quad];
        uint4 tr1 = RootE[(size_t)r1 * 16 + kt * 4 + quad];
        ta0.x = encdec(ta0.x); ta0.y = encdec(ta0.y); ta0.z = encdec(ta0.z); ta0.w = encdec(ta0.w);
        ta1.x = encdec(ta1.x); ta1.y = encdec(ta1.y); ta1.z = encdec(ta1.z); ta1.w = encdec(ta1.w);
        tr0.x = encdec(tr0.x); tr0.y = encdec(tr0.y); tr0.z = encdec(tr0.z); tr0.w = encdec(tr0.w);
        tr1.x = encdec(tr1.x); tr1.y = encdec(tr1.y); tr1.z = encdec(tr1.z); tr1.w = encdec(tr1.w);
        bf16x8 aa0 = __builtin_bit_cast(bf16x8, ta0);
        bf16x8 aa1 = __builtin_bit_cast(bf16x8, ta1);
        bf16x8 ar0 = __builtin_bit_cast(bf16x8, tr0);
        bf16x8 ar1 = __builtin_bit_cast(bf16x8, tr1);
#pragma unroll
        for (int nt = 0; nt < NT; ++nt) {
            bf16x8 b0 = __builtin_bit_cast(bf16x8, Wf[(kt * NT + nt) * 64 + lane]);
            acc[0][nt] = __builtin_amdgcn_mfma_f32_16x16x32_bf16(aa0, b0, acc[0][nt], 0, 0, 0);
            acc[1][nt] = __builtin_amdgcn_mfma_f32_16x16x32_bf16(aa1, b0, acc[1][nt], 0, 0, 0);
            bf16x8 b1 = __builtin_bit_cast(bf16x8, Wf[((4 + kt) * NT + nt) * 64 + lane]);
            acc[0][nt] = __builtin_amdgcn_mfma_f32_16x16x32_bf16(ar0, b1, acc[0][nt], 0, 0, 0);
            acc[1][nt] = __builtin_amdgcn_mfma_f32_16x16x32_bf16(ar1, b1, acc[1][nt], 0, 0, 0);
        }
    }

    // epilogue: D layout col=lane&15, row=quad*4+reg
#pragma unroll
    for (int mt = 0; mt < 2; ++mt) {
        const int rowD = base0 + mt * 16 + quad * 4;
#pragma unroll
        for (int nt = 0; nt < NT; ++nt) {
            int col = nt * 16 + mrow;
            float bv = bias[col];
#pragma unroll
            for (int r = 0; r < 4; ++r) {
                int grow = rowD + r;
                if (grow < M) {
                    float v = acc[mt][nt][r] + bv;
                    if (RELU) v = fmaxf(v, 0.0f);
                    if constexpr (ENCOUT) {
                        unsigned u = f2bf_rne(v);
                        u ^= ((u >> 15) & 1u) * 0x7FFFu;   // encode for next layer
                        C[(size_t)grow * BN + col] = (OutT)u;
                    } else {
                        C[(size_t)grow * BN + col] = (OutT)v;
                    }
                }
            }
        }
    }
}

extern "C" void kernel_launch(void* const* d_in, const int* in_sizes, int n_in,
                              void* d_out, int out_size, void* d_ws, size_t ws_size,
                              hipStream_t stream) {
    const float* x   = (const float*)d_in[0];
    const int*   ei  = (const int*)d_in[1];
    const float* W1l = (const float*)d_in[2];
    const float* b1l = (const float*)d_in[3];
    const float* W1r = (const float*)d_in[4];
    const float* W2l = (const float*)d_in[5];
    const float* b2l = (const float*)d_in[6];
    const float* W2r = (const float*)d_in[7];
    float* out = (float*)d_out;

    const int* src = ei;
    const int* dst = ei + NEDGES;

    // ---- workspace layout ----
    char* ws = (char*)d_ws;
    unsigned short* xe    = (unsigned short*)ws; ws += (size_t)NNODES * 128 * 2;  // 25.6 MB (encoded)
    unsigned short* he    = (unsigned short*)ws; ws += (size_t)NNODES * 128 * 2;  // 25.6 MB (encoded)
    unsigned short* aggrE = (unsigned short*)ws; ws += (size_t)NNODES * 128 * 2;  // 25.6 MB (encoded)
    unsigned int* binArr    = (unsigned int*)ws; ws += (size_t)NBKT * CAP * 4;    // 7.2 MB
    unsigned int* sortedSrc = (unsigned int*)ws; ws += (size_t)NBKT * CAP * 4;    // 7.2 MB
    int* rowBeg     = (int*)ws; ws += (size_t)NNODES * 4;
    int* rowEnd     = (int*)ws; ws += (size_t)NNODES * 4;
    int* bucketFill = (int*)ws; ws += 256 * 4;
    uint4* Wf1 = (uint4*)ws; ws += 4096 * 16;   // 64 KB fragment-packed L1 weights
    uint4* Wf2 = (uint4*)ws; ws += 2048 * 16;   // 32 KB fragment-packed L2 weights

    const int gAgg = NNODES / 32;            // 3125 (exact: 32 nodes per block)
    const int gGemm = (NNODES + 127) / 128;  // 782

    prep1_kernel<<<25, 256, 0, stream>>>(W1l, W1r, W2l, W2r, Wf1, Wf2, bucketFill);
    prep2_kernel<<<GBIN + GCVT, 256, 0, stream>>>(src, dst, binArr, bucketFill,
                                                  (const float4*)x, (uint4*)xe, NEDGES);
    build_csr_kernel<<<NBKT, 512, 0, stream>>>(binArr, bucketFill, sortedSrc, rowBeg, rowEnd);

    // ---- layer 1 ----
    aggregate_pipe<<<gAgg, 256, 0, stream>>>((const uint4*)xe, rowBeg, rowEnd, sortedSrc,
                                             (uint4*)aggrE);
    sage_gemm_lean<128, true, true, unsigned short><<<gGemm, 256, 0, stream>>>(
        (const uint4*)aggrE, (const uint4*)xe, Wf1, b1l, he, NNODES);
    // ---- layer 2 ----
    aggregate_pipe<<<gAgg, 256, 0, stream>>>((const uint4*)he, rowBeg, rowEnd, sortedSrc,
                                             (uint4*)aggrE);
    sage_gemm_lean<64, false, false, float><<<gGemm, 256, 0, stream>>>(
        (const uint4*)aggrE, (const uint4*)he, Wf2, b2l, out, NNODES);
}

// Round 3
// 294.684 us; speedup vs baseline: 1.0177x; 1.0177x over previous
//
#include <hip/hip_runtime.h>
#include <cstdint>

#define NNODES 100000
#define NEDGES 1600000
#define NBKT   196          // ceil(NNODES / 512); bucket = dst >> 9
#define CAP    9216         // per-bucket capacity: mean 8192 + ~11 sigma
#define BIN_CHUNK 4096
#define GBIN ((NEDGES + BIN_CHUNK - 1) / BIN_CHUNK)   // 391
#define GCVT (NNODES * 128 / 8 / 256)                 // 6250 (8 floats/thread)

typedef __attribute__((ext_vector_type(8))) __bf16 bf16x8;
typedef __attribute__((ext_vector_type(4))) float f32x4;
typedef short v2s __attribute__((ext_vector_type(2)));

__device__ __forceinline__ unsigned short f2bf_rne(float f) {
    unsigned int u = __float_as_uint(f);
    u += 0x7fffu + ((u >> 16) & 1u);
    return (unsigned short)(u >> 16);
}
// involutive monotone map: bf16 float order <-> signed i16 order (per packed half)
__device__ __forceinline__ unsigned encdec(unsigned u) {
    return u ^ (((u & 0x80008000u) >> 15) * 0x7FFFu);
}
__device__ __forceinline__ unsigned pkmax(unsigned a, unsigned b) {
    v2s r = __builtin_elementwise_max(__builtin_bit_cast(v2s, a), __builtin_bit_cast(v2s, b));
    return __builtin_bit_cast(unsigned, r);
}

// ---------------- prep1: zero bucketFill + pack weights into MFMA B-fragment
__global__ __launch_bounds__(256) void prep1_kernel(
        const float* __restrict__ W1l, const float* __restrict__ W1r,
        const float* __restrict__ W2l, const float* __restrict__ W2r,
        uint4* __restrict__ Wf1, uint4* __restrict__ Wf2,
        int* __restrict__ bucketFill) {
    if (blockIdx.x == 24) { bucketFill[threadIdx.x] = 0; return; }
    int t = blockIdx.x * 256 + threadIdx.x;   // 0..6143
    unsigned short s[8];
    if (t < 4096) {                           // layer 1: BN=128, NT=8
        int h = t >> 11, kt = (t >> 9) & 3, nt = (t >> 6) & 7, lane = t & 63;
        const float* W = h ? W1r : W1l;
        int k0 = kt * 32 + (lane >> 4) * 8;
        int col = nt * 16 + (lane & 15);
#pragma unroll
        for (int j = 0; j < 8; ++j) s[j] = f2bf_rne(W[(k0 + j) * 128 + col]);
        uint4 o;
        o.x = (unsigned)s[0] | ((unsigned)s[1] << 16);
        o.y = (unsigned)s[2] | ((unsigned)s[3] << 16);
        o.z = (unsigned)s[4] | ((unsigned)s[5] << 16);
        o.w = (unsigned)s[6] | ((unsigned)s[7] << 16);
        Wf1[t] = o;
    } else {                                  // layer 2: BN=64, NT=4
        int u = t - 4096;                     // 0..2047
        int h = u >> 10, kt = (u >> 8) & 3, nt = (u >> 6) & 3, lane = u & 63;
        const float* W = h ? W2r : W2l;
        int k0 = kt * 32 + (lane >> 4) * 8;
        int col = nt * 16 + (lane & 15);
#pragma unroll
        for (int j = 0; j < 8; ++j) s[j] = f2bf_rne(W[(k0 + j) * 64 + col]);
        uint4 o;
        o.x = (unsigned)s[0] | ((unsigned)s[1] << 16);
        o.y = (unsigned)s[2] | ((unsigned)s[3] << 16);
        o.z = (unsigned)s[4] | ((unsigned)s[5] << 16);
        o.w = (unsigned)s[6] | ((unsigned)s[7] << 16);
        Wf2[u] = o;
    }
}

// ---------------- prep2: bin edges (blocks [0,GBIN)) + encode x (rest) --------
__global__ __launch_bounds__(256) void prep2_kernel(
        const int* __restrict__ src, const int* __restrict__ dst,
        unsigned int* __restrict__ binArr, int* __restrict__ bucketFill,
        const float4* __restrict__ xin, uint4* __restrict__ xeout, int nE) {
    if (blockIdx.x >= GBIN) {
        int i = (blockIdx.x - GBIN) * 256 + threadIdx.x;  // < 1.6M
        float4 v0 = xin[(size_t)2 * i], v1 = xin[(size_t)2 * i + 1];
        uint4 o;
        o.x = encdec((unsigned)f2bf_rne(v0.x) | ((unsigned)f2bf_rne(v0.y) << 16));
        o.y = encdec((unsigned)f2bf_rne(v0.z) | ((unsigned)f2bf_rne(v0.w) << 16));
        o.z = encdec((unsigned)f2bf_rne(v1.x) | ((unsigned)f2bf_rne(v1.y) << 16));
        o.w = encdec((unsigned)f2bf_rne(v1.z) | ((unsigned)f2bf_rne(v1.w) << 16));
        xeout[i] = o;
        return;
    }
    // ---- bin: entry = (dst&511)<<17 | src ----
    __shared__ unsigned int stage[BIN_CHUNK];
    __shared__ unsigned char bof[BIN_CHUNK];
    __shared__ int cnt[256], cstart[256], cfill[256], gbase[256];
    const int tid = threadIdx.x;
    const int blockStart = blockIdx.x * BIN_CHUNK;
    const int chunkN = min(BIN_CHUNK, nE - blockStart);
    cnt[tid] = 0;
    __syncthreads();
    int myd[16], mys[16];
#pragma unroll
    for (int i = 0; i < 16; ++i) {
        int idx = i * 256 + tid;
        if (idx < chunkN) {
            myd[i] = dst[blockStart + idx];
            mys[i] = src[blockStart + idx];
            atomicAdd(&cnt[myd[i] >> 9], 1);
        }
    }
    __syncthreads();
    int v = cnt[tid];
    for (int off = 1; off < 256; off <<= 1) {
        int add = (tid >= off) ? cnt[tid - off] : 0;
        __syncthreads();
        cnt[tid] += add;
        __syncthreads();
    }
    cstart[tid] = cnt[tid] - v;
    cfill[tid] = cnt[tid] - v;
    if (tid < NBKT && v > 0) gbase[tid] = atomicAdd(&bucketFill[tid], v);
    __syncthreads();
#pragma unroll
    for (int i = 0; i < 16; ++i) {
        int idx = i * 256 + tid;
        if (idx < chunkN) {
            int b = myd[i] >> 9;
            int p = atomicAdd(&cfill[b], 1);
            stage[p] = ((unsigned)(myd[i] & 511) << 17) | (unsigned)mys[i];
            bof[p] = (unsigned char)b;
        }
    }
    __syncthreads();
#pragma unroll
    for (int i = 0; i < 16; ++i) {
        int idx = i * 256 + tid;
        if (idx < chunkN) {
            int b = bof[idx];
            int slot = gbase[b] + (idx - cstart[b]);
            if (slot < CAP) binArr[(size_t)b * CAP + slot] = stage[idx];
        }
    }
}

// ---------------- per-bucket CSR build, all in LDS ----------------
__global__ __launch_bounds__(512) void build_csr_kernel(
        const unsigned int* __restrict__ binArr, const int* __restrict__ bucketFill,
        unsigned int* __restrict__ sortedSrc,
        int* __restrict__ rowBeg, int* __restrict__ rowEnd) {
    __shared__ unsigned int stage[CAP];
    __shared__ int ncnt[512], nstart[512];
    const int b = blockIdx.x;
    const int t = threadIdx.x;
    const int cnt_b = min(bucketFill[b], CAP);
    ncnt[t] = 0;
    __syncthreads();
    for (int i = t; i < cnt_b; i += 512) {
        unsigned int e = binArr[(size_t)b * CAP + i];
        stage[i] = e;
        atomicAdd(&ncnt[e >> 17], 1);
    }
    __syncthreads();
    int v = ncnt[t];
    for (int off = 1; off < 512; off <<= 1) {
        int add = (t >= off) ? ncnt[t - off] : 0;
        __syncthreads();
        ncnt[t] += add;
        __syncthreads();
    }
    int start = ncnt[t] - v;
    nstart[t] = start;
    int n = (b << 9) + t;
    if (n < NNODES) {
        rowBeg[n] = b * CAP + start;
        rowEnd[n] = b * CAP + start + v;
    }
    __syncthreads();
    for (int i = t; i < cnt_b; i += 512) {
        unsigned int e = stage[i];
        int p = atomicAdd(&nstart[e >> 17], 1);
        sortedSrc[(size_t)b * CAP + p] = e & 0x1FFFFu;
    }
}

// ---------------- aggregation: 2 nodes/wave, 12500 blocks, 8 gathers live ----
// R2: R0's high-occupancy grid + R1's unconditional round-0 (8 loads in flight).
// Output stays ENCODED (decode happens in the GEMM fragment load).
__global__ __launch_bounds__(256) void aggregate_mlp(
        const uint4* __restrict__ xe4,          // [M][16] encoded bf16
        const int* __restrict__ rowBeg,
        const int* __restrict__ rowEnd,
        const unsigned int* __restrict__ sortedSrc,
        uint4* __restrict__ aggrE,              // [M][16] encoded bf16
        int nN) {
    const int wv = threadIdx.x >> 6;
    const int lane = threadIdx.x & 63;
    const int grp = lane >> 4;
    const int col = lane & 15;
    const int nA = blockIdx.x * 8 + wv * 2;
    const int nB = nA + 1;
    if (nA >= nN) return;
    const int begA = rowBeg[nA], endA = rowEnd[nA];
    int begB = 0, endB = 0;
    if (nB < nN) { begB = rowBeg[nB]; endB = rowEnd[nB]; }
    const int mA = endA - begA, mB = endB - begB;

    int idA = (mA > 0) ? (int)sortedSrc[min(begA + lane, endA - 1)] : 0;
    int idB = (mB > 0) ? (int)sortedSrc[min(begB + lane, endB - 1)] : 0;

    // round 0: unconditional 8 gathers (clamp-replicated ids are safe; deg-0
    // nodes gather row 0 and the result is discarded at the write)
    int sA0 = __shfl(idA, grp),     sA1 = __shfl(idA, 4 + grp);
    int sA2 = __shfl(idA, 8 + grp), sA3 = __shfl(idA, 12 + grp);
    int sB0 = __shfl(idB, grp),     sB1 = __shfl(idB, 4 + grp);
    int sB2 = __shfl(idB, 8 + grp), sB3 = __shfl(idB, 12 + grp);
    uint4 pA0 = xe4[(size_t)sA0 * 16 + col];
    uint4 pA1 = xe4[(size_t)sA1 * 16 + col];
    uint4 pA2 = xe4[(size_t)sA2 * 16 + col];
    uint4 pA3 = xe4[(size_t)sA3 * 16 + col];
    uint4 pB0 = xe4[(size_t)sB0 * 16 + col];
    uint4 pB1 = xe4[(size_t)sB1 * 16 + col];
    uint4 pB2 = xe4[(size_t)sB2 * 16 + col];
    uint4 pB3 = xe4[(size_t)sB3 * 16 + col];

    unsigned aA0 = pkmax(pkmax(pA0.x, pA1.x), pkmax(pA2.x, pA3.x));
    unsigned aA1 = pkmax(pkmax(pA0.y, pA1.y), pkmax(pA2.y, pA3.y));
    unsigned aA2 = pkmax(pkmax(pA0.z, pA1.z), pkmax(pA2.z, pA3.z));
    unsigned aA3 = pkmax(pkmax(pA0.w, pA1.w), pkmax(pA2.w, pA3.w));
    unsigned aB0 = pkmax(pkmax(pB0.x, pB1.x), pkmax(pB2.x, pB3.x));
    unsigned aB1 = pkmax(pkmax(pB0.y, pB1.y), pkmax(pB2.y, pB3.y));
    unsigned aB2 = pkmax(pkmax(pB0.z, pB1.z), pkmax(pB2.z, pB3.z));
    unsigned aB3 = pkmax(pkmax(pB0.w, pB1.w), pkmax(pB2.w, pB3.w));

    // extra rounds for degree 17..64
    const int cA = min(mA, 64), cB = min(mB, 64);
    const int mm = max(cA, cB);
    for (int j = 16; j < mm; j += 16) {
        const bool doA = j < cA, doB = j < cB;
        uint4 qA0, qA1, qA2, qA3, qB0, qB1, qB2, qB3;
        if (doA) {
            int s0 = __shfl(idA, j + grp);
            int s1 = __shfl(idA, j + 4 + grp);
            int s2 = __shfl(idA, j + 8 + grp);
            int s3 = __shfl(idA, j + 12 + grp);
            qA0 = xe4[(size_t)s0 * 16 + col];
            qA1 = xe4[(size_t)s1 * 16 + col];
            qA2 = xe4[(size_t)s2 * 16 + col];
            qA3 = xe4[(size_t)s3 * 16 + col];
        }
        if (doB) {
            int s0 = __shfl(idB, j + grp);
            int s1 = __shfl(idB, j + 4 + grp);
            int s2 = __shfl(idB, j + 8 + grp);
            int s3 = __shfl(idB, j + 12 + grp);
            qB0 = xe4[(size_t)s0 * 16 + col];
            qB1 = xe4[(size_t)s1 * 16 + col];
            qB2 = xe4[(size_t)s2 * 16 + col];
            qB3 = xe4[(size_t)s3 * 16 + col];
        }
        if (doA) {
            aA0 = pkmax(aA0, pkmax(pkmax(qA0.x, qA1.x), pkmax(qA2.x, qA3.x)));
            aA1 = pkmax(aA1, pkmax(pkmax(qA0.y, qA1.y), pkmax(qA2.y, qA3.y)));
            aA2 = pkmax(aA2, pkmax(pkmax(qA0.z, qA1.z), pkmax(qA2.z, qA3.z)));
            aA3 = pkmax(aA3, pkmax(pkmax(qA0.w, qA1.w), pkmax(qA2.w, qA3.w)));
        }
        if (doB) {
            aB0 = pkmax(aB0, pkmax(pkmax(qB0.x, qB1.x), pkmax(qB2.x, qB3.x)));
            aB1 = pkmax(aB1, pkmax(pkmax(qB0.y, qB1.y), pkmax(qB2.y, qB3.y)));
            aB2 = pkmax(aB2, pkmax(pkmax(qB0.z, qB1.z), pkmax(qB2.z, qB3.z)));
            aB3 = pkmax(aB3, pkmax(pkmax(qB0.w, qB1.w), pkmax(qB2.w, qB3.w)));
        }
    }
    // degree > 64 tails (Poisson(16): essentially never, kept for safety)
    for (int bs = begA + 64; bs < endA; bs += 64) {
        int bid = (int)sortedSrc[min(bs + lane, endA - 1)];
        const int m = min(endA - bs, 64);
        for (int j = 0; j < m; j += 16) {
            int s0 = __shfl(bid, j + grp);
            int s1 = __shfl(bid, j + 4 + grp);
            int s2 = __shfl(bid, j + 8 + grp);
            int s3 = __shfl(bid, j + 12 + grp);
            uint4 q0 = xe4[(size_t)s0 * 16 + col];
            uint4 q1 = xe4[(size_t)s1 * 16 + col];
            uint4 q2 = xe4[(size_t)s2 * 16 + col];
            uint4 q3 = xe4[(size_t)s3 * 16 + col];
            aA0 = pkmax(aA0, pkmax(pkmax(q0.x, q1.x), pkmax(q2.x, q3.x)));
            aA1 = pkmax(aA1, pkmax(pkmax(q0.y, q1.y), pkmax(q2.y, q3.y)));
            aA2 = pkmax(aA2, pkmax(pkmax(q0.z, q1.z), pkmax(q2.z, q3.z)));
            aA3 = pkmax(aA3, pkmax(pkmax(q0.w, q1.w), pkmax(q2.w, q3.w)));
        }
    }
    for (int bs = begB + 64; bs < endB; bs += 64) {
        int bid = (int)sortedSrc[min(bs + lane, endB - 1)];
        const int m = min(endB - bs, 64);
        for (int j = 0; j < m; j += 16) {
            int s0 = __shfl(bid, j + grp);
            int s1 = __shfl(bid, j + 4 + grp);
            int s2 = __shfl(bid, j + 8 + grp);
            int s3 = __shfl(bid, j + 12 + grp);
            uint4 q0 = xe4[(size_t)s0 * 16 + col];
            uint4 q1 = xe4[(size_t)s1 * 16 + col];
            uint4 q2 = xe4[(size_t)s2 * 16 + col];
            uint4 q3 = xe4[(size_t)s3 * 16 + col];
            aB0 = pkmax(aB0, pkmax(pkmax(q0.x, q1.x), pkmax(q2.x, q3.x)));
            aB1 = pkmax(aB1, pkmax(pkmax(q0.y, q1.y), pkmax(q2.y, q3.y)));
            aB2 = pkmax(aB2, pkmax(pkmax(q0.z, q1.z), pkmax(q2.z, q3.z)));
            aB3 = pkmax(aB3, pkmax(pkmax(q0.w, q1.w), pkmax(q2.w, q3.w)));
        }
    }
    // merge the 4 edge-groups (lane bits 4,5) -> all lanes hold the result
    aA0 = pkmax(aA0, (unsigned)__shfl_xor((int)aA0, 16));
    aA1 = pkmax(aA1, (unsigned)__shfl_xor((int)aA1, 16));
    aA2 = pkmax(aA2, (unsigned)__shfl_xor((int)aA2, 16));
    aA3 = pkmax(aA3, (unsigned)__shfl_xor((int)aA3, 16));
    aB0 = pkmax(aB0, (unsigned)__shfl_xor((int)aB0, 16));
    aB1 = pkmax(aB1, (unsigned)__shfl_xor((int)aB1, 16));
    aB2 = pkmax(aB2, (unsigned)__shfl_xor((int)aB2, 16));
    aB3 = pkmax(aB3, (unsigned)__shfl_xor((int)aB3, 16));
    aA0 = pkmax(aA0, (unsigned)__shfl_xor((int)aA0, 32));
    aA1 = pkmax(aA1, (unsigned)__shfl_xor((int)aA1, 32));
    aA2 = pkmax(aA2, (unsigned)__shfl_xor((int)aA2, 32));
    aA3 = pkmax(aA3, (unsigned)__shfl_xor((int)aA3, 32));
    aB0 = pkmax(aB0, (unsigned)__shfl_xor((int)aB0, 32));
    aB1 = pkmax(aB1, (unsigned)__shfl_xor((int)aB1, 32));
    aB2 = pkmax(aB2, (unsigned)__shfl_xor((int)aB2, 32));
    aB3 = pkmax(aB3, (unsigned)__shfl_xor((int)aB3, 32));
    // lanes 0..15 write node A's row, lanes 16..31 write node B's
    if (lane < 16) {
        uint4 o;
        if (mA > 0) { o.x = aA0; o.y = aA1; o.z = aA2; o.w = aA3; }
        else        { o.x = o.y = o.z = o.w = 0u; }          // enc(0)==0
        aggrE[(size_t)nA * 16 + lane] = o;
    } else if (lane < 32 && nB < nN) {
        uint4 o;
        if (mB > 0) { o.x = aB0; o.y = aB1; o.z = aB2; o.w = aB3; }
        else        { o.x = o.y = o.z = o.w = 0u; }
        aggrE[(size_t)nB * 16 + (lane - 16)] = o;
    }
}

// ---------------- lean SAGE GEMM: no LDS, no barriers ----------------
template<int BN, bool RELU, bool ENCOUT, typename OutT>
__global__ __launch_bounds__(256, 4) void sage_gemm_lean(
        const uint4* __restrict__ AggE,            // [M][16] encoded bf16
        const uint4* __restrict__ RootE,           // [M][16] encoded bf16
        const uint4* __restrict__ Wf,              // fragment-packed weights
        const float* __restrict__ bias,            // [BN] f32
        OutT* __restrict__ C,                      // [M][BN]
        int M) {
    constexpr int NT = BN / 16;
    const int tid = threadIdx.x;
    const int w = tid >> 6;
    const int lane = tid & 63;
    const int quad = lane >> 4;
    const int mrow = lane & 15;
    const int base0 = blockIdx.x * 128 + w * 32;

    const int r0 = min(base0 + mrow, M - 1);
    const int r1 = min(base0 + 16 + mrow, M - 1);

    f32x4 acc[2][NT];
#pragma unroll
    for (int mt = 0; mt < 2; ++mt)
#pragma unroll
        for (int nt = 0; nt < NT; ++nt) acc[mt][nt] = (f32x4){0.f, 0.f, 0.f, 0.f};

#pragma unroll
    for (int kt = 0; kt < 4; ++kt) {
        uint4 ta0 = AggE[(size_t)r0 * 16 + kt * 4 + quad];
        uint4 ta1 = AggE[(size_t)r1 * 16 + kt * 4 + quad];
        uint4 tr0 = RootE[(size_t)r0 * 16 + kt * 4 + quad];
        uint4 tr1 = RootE[(size_t)r1 * 16 + kt * 4 + quad];
        ta0.x = encdec(ta0.x); ta0.y = encdec(ta0.y); ta0.z = encdec(ta0.z); ta0.w = encdec(ta0.w);
        ta1.x = encdec(ta1.x); ta1.y = encdec(ta1.y); ta1.z = encdec(ta1.z); ta1.w = encdec(ta1.w);
        tr0.x = encdec(tr0.x); tr0.y = encdec(tr0.y); tr0.z = encdec(tr0.z); tr0.w = encdec(tr0.w);
        tr1.x = encdec(tr1.x); tr1.y = encdec(tr1.y); tr1.z = encdec(tr1.z); tr1.w = encdec(tr1.w);
        bf16x8 aa0 = __builtin_bit_cast(bf16x8, ta0);
        bf16x8 aa1 = __builtin_bit_cast(bf16x8, ta1);
        bf16x8 ar0 = __builtin_bit_cast(bf16x8, tr0);
        bf16x8 ar1 = __builtin_bit_cast(bf16x8, tr1);
#pragma unroll
        for (int nt = 0; nt < NT; ++nt) {
            bf16x8 b0 = __builtin_bit_cast(bf16x8, Wf[(kt * NT + nt) * 64 + lane]);
            acc[0][nt] = __builtin_amdgcn_mfma_f32_16x16x32_bf16(aa0, b0, acc[0][nt], 0, 0, 0);
            acc[1][nt] = __builtin_amdgcn_mfma_f32_16x16x32_bf16(aa1, b0, acc[1][nt], 0, 0, 0);
            bf16x8 b1 = __builtin_bit_cast(bf16x8, Wf[((4 + kt) * NT + nt) * 64 + lane]);
            acc[0][nt] = __builtin_amdgcn_mfma_f32_16x16x32_bf16(ar0, b1, acc[0][nt], 0, 0, 0);
            acc[1][nt] = __builtin_amdgcn_mfma_f32_16x16x32_bf16(ar1, b1, acc[1][nt], 0, 0, 0);
        }
    }

    // epilogue: D layout col=lane&15, row=quad*4+reg
#pragma unroll
    for (int mt = 0; mt < 2; ++mt) {
        const int rowD = base0 + mt * 16 + quad * 4;
#pragma unroll
        for (int nt = 0; nt < NT; ++nt) {
            int col = nt * 16 + mrow;
            float bv = bias[col];
#pragma unroll
            for (int r = 0; r < 4; ++r) {
                int grow = rowD + r;
                if (grow < M) {
                    float v = acc[mt][nt][r] + bv;
                    if (RELU) v = fmaxf(v, 0.0f);
                    if constexpr (ENCOUT) {
                        unsigned u = f2bf_rne(v);
                        u ^= ((u >> 15) & 1u) * 0x7FFFu;   // encode for next layer
                        C[(size_t)grow * BN + col] = (OutT)u;
                    } else {
                        C[(size_t)grow * BN + col] = (OutT)v;
                    }
                }
            }
        }
    }
}

extern "C" void kernel_launch(void* const* d_in, const int* in_sizes, int n_in,
                              void* d_out, int out_size, void* d_ws, size_t ws_size,
                              hipStream_t stream) {
    const float* x   = (const float*)d_in[0];
    const int*   ei  = (const int*)d_in[1];
    const float* W1l = (const float*)d_in[2];
    const float* b1l = (const float*)d_in[3];
    const float* W1r = (const float*)d_in[4];
    const float* W2l = (const float*)d_in[5];
    const float* b2l = (const float*)d_in[6];
    const float* W2r = (const float*)d_in[7];
    float* out = (float*)d_out;

    const int* src = ei;
    const int* dst = ei + NEDGES;

    // ---- workspace layout ----
    char* ws = (char*)d_ws;
    unsigned short* xe    = (unsigned short*)ws; ws += (size_t)NNODES * 128 * 2;  // 25.6 MB (encoded)
    unsigned short* he    = (unsigned short*)ws; ws += (size_t)NNODES * 128 * 2;  // 25.6 MB (encoded)
    unsigned short* aggrE = (unsigned short*)ws; ws += (size_t)NNODES * 128 * 2;  // 25.6 MB (encoded)
    unsigned int* binArr    = (unsigned int*)ws; ws += (size_t)NBKT * CAP * 4;    // 7.2 MB
    unsigned int* sortedSrc = (unsigned int*)ws; ws += (size_t)NBKT * CAP * 4;    // 7.2 MB
    int* rowBeg     = (int*)ws; ws += (size_t)NNODES * 4;
    int* rowEnd     = (int*)ws; ws += (size_t)NNODES * 4;
    int* bucketFill = (int*)ws; ws += 256 * 4;
    uint4* Wf1 = (uint4*)ws; ws += 4096 * 16;   // 64 KB fragment-packed L1 weights
    uint4* Wf2 = (uint4*)ws; ws += 2048 * 16;   // 32 KB fragment-packed L2 weights

    const int gAgg = (NNODES + 7) / 8;       // 12500 (2 nodes per wave)
    const int gGemm = (NNODES + 127) / 128;  // 782

    prep1_kernel<<<25, 256, 0, stream>>>(W1l, W1r, W2l, W2r, Wf1, Wf2, bucketFill);
    prep2_kernel<<<GBIN + GCVT, 256, 0, stream>>>(src, dst, binArr, bucketFill,
                                                  (const float4*)x, (uint4*)xe, NEDGES);
    build_csr_kernel<<<NBKT, 512, 0, stream>>>(binArr, bucketFill, sortedSrc, rowBeg, rowEnd);

    // ---- layer 1 ----
    aggregate_mlp<<<gAgg, 256, 0, stream>>>((const uint4*)xe, rowBeg, rowEnd, sortedSrc,
                                            (uint4*)aggrE, NNODES);
    sage_gemm_lean<128, true, true, unsigned short><<<gGemm, 256, 0, stream>>>(
        (const uint4*)aggrE, (const uint4*)xe, Wf1, b1l, he, NNODES);
    // ---- layer 2 ----
    aggregate_mlp<<<gAgg, 256, 0, stream>>>((const uint4*)he, rowBeg, rowEnd, sortedSrc,
                                            (uint4*)aggrE, NNODES);
    sage_gemm_lean<64, false, false, float><<<gGemm, 256, 0, stream>>>(
        (const uint4*)aggrE, (const uint4*)he, Wf2, b2l, out, NNODES);
}